// Round 4
// baseline (136.047 us; speedup 1.0000x reference)
//
#include <hip/hip_runtime.h>

// Problem constants (from setup_inputs): N=4096, C=64, A=256
#define N_ROWS 4096
#define C_CLS  64
#define A_DIM  256
#define BK     32           // K-chunk (over b) per phase-1 block
#define KCHUNK (A_DIM / BK) // 8
#define NBLK   (C_CLS * KCHUNK)   // 512 blocks
#define LOSS_BLOCKS 128
#define FLAG_READY 1u

// ---------------------------------------------------------------------------
// Fused kernel, 512 blocks x 256 threads, all co-resident (48KB LDS -> 3/CU,
// VGPR ~140 -> >=2 blocks/CU; 512 <= 2*256 so the flag-spin cannot deadlock).
//
// Phase 0 (blocks 0..127): prefetch pred/labels for the loss phase into
//   registers — loads stay in flight across the whole qform phase.
// Phase 1 (all 512): Spart[kc][y][c] = partial-b-chunk of
//   (w_c-w_y)^T CV[y] (w_c-w_y); CV symmetric -> row reads.
//   Then release-fence + flags[b] = 1. Blocks 128..511 retire (free CUs).
// Phase 2 (blocks 0..127): spin on all 512 flags (poison 0xAA != 1, so no
//   init dispatch needed), acquire-fence, then softmax-CE on
//   pred + 0.5*Lambda*sum_kc Spart; one device atomicAdd per block into out.
// ---------------------------------------------------------------------------
__global__ __launch_bounds__(256) void fused_kernel(
    const float* __restrict__ W,       // [C][A]
    const float* __restrict__ CV,      // [C][A][A]
    const float* __restrict__ pred,    // [N][C]
    const int*   __restrict__ labels,  // [N]
    const float* __restrict__ lambda_p,
    float* __restrict__ Spart,         // ws: [KCHUNK][C][C]
    unsigned int* __restrict__ flags,  // ws: [NBLK]
    float* __restrict__ out)           // [1]
{
    __shared__ float Vt[BK][A_DIM];   // 32 KB
    __shared__ float Dt[BK][C_CLS];   //  8 KB
    __shared__ float Psum[32][C_CLS]; //  8 KB
    __shared__ float wsum[4];

    const int t  = threadIdx.x;
    const int b  = blockIdx.x;
    const int lane = t & 63;
    const int y  = b >> 3;
    const int kc = b & 7;
    const int kb = kc * BK;

    // ---- phase 0: prefetch loss inputs (blocks 0..127) ----
    float pf_pred[8];
    int   pf_y[8];
    const int wgid = b * 4 + (t >> 6);   // 0..511 for b<128
    if (b < LOSS_BLOCKS) {
        #pragma unroll
        for (int r = 0; r < 8; ++r) {
            const int n = r * 512 + wgid;
            pf_y[r]    = labels[n];
            pf_pred[r] = pred[n * C_CLS + lane];
        }
    }
    if (b == 0 && t == 0) out[0] = 0.0f;   // visible to all loss atomics via barrier

    // ---- phase 1: stage Vt (rows kb..kb+31 of CV[y], contiguous, coalesced) ----
    {
        const float4* src = (const float4*)(CV + ((size_t)y * A_DIM * A_DIM
                                                  + (size_t)kb * A_DIM));
        float4* vdst = (float4*)&Vt[0][0];
        #pragma unroll
        for (int i = 0; i < (BK * A_DIM / 4) / 256; ++i)
            vdst[t + i * 256] = src[t + i * 256];
    }
    // stage Dt (transposed diff chunk)
    {
        const int kq    = (t & 7) * 4;
        const int chalf = t >> 3;
        const float4 wy = *(const float4*)(W + y * A_DIM + kb + kq);
        #pragma unroll
        for (int cc = 0; cc < 2; ++cc) {
            const int c = chalf + cc * 32;
            const float4 wc = *(const float4*)(W + c * A_DIM + kb + kq);
            Dt[kq + 0][c] = wc.x - wy.x;
            Dt[kq + 1][c] = wc.y - wy.y;
            Dt[kq + 2][c] = wc.z - wy.z;
            Dt[kq + 3][c] = wc.w - wy.w;
        }
    }
    __syncthreads();

    // 8x8 register tile: c0=(t%8)*8 covers 64 c, a0=(t/8)*8 covers 256 a
    const int c0 = (t & 7) * 8;
    const int a0 = (t >> 3) * 8;
    float acc[8][8];
    #pragma unroll
    for (int i = 0; i < 8; ++i)
        #pragma unroll
        for (int j = 0; j < 8; ++j) acc[i][j] = 0.0f;

    #pragma unroll 2
    for (int k = 0; k < BK; ++k) {
        const float4 a_lo = *(const float4*)&Vt[k][a0];
        const float4 a_hi = *(const float4*)&Vt[k][a0 + 4];
        const float4 d_lo = *(const float4*)&Dt[k][c0];
        const float4 d_hi = *(const float4*)&Dt[k][c0 + 4];
        const float af[8] = {a_lo.x, a_lo.y, a_lo.z, a_lo.w,
                             a_hi.x, a_hi.y, a_hi.z, a_hi.w};
        const float df[8] = {d_lo.x, d_lo.y, d_lo.z, d_lo.w,
                             d_hi.x, d_hi.y, d_hi.z, d_hi.w};
        #pragma unroll
        for (int i = 0; i < 8; ++i)
            #pragma unroll
            for (int j = 0; j < 8; ++j)
                acc[i][j] += df[i] * af[j];
    }

    // fused epilogue: s_i = sum_j acc[i][j] * (W[c0+i][a0+j] - W[y][a0+j])
    float s[8];
    {
        const float4 wy_lo = *(const float4*)(W + y * A_DIM + a0);
        const float4 wy_hi = *(const float4*)(W + y * A_DIM + a0 + 4);
        const float wyv[8] = {wy_lo.x, wy_lo.y, wy_lo.z, wy_lo.w,
                              wy_hi.x, wy_hi.y, wy_hi.z, wy_hi.w};
        #pragma unroll
        for (int i = 0; i < 8; ++i) {
            const int c = c0 + i;
            const float4 wc_lo = *(const float4*)(W + c * A_DIM + a0);
            const float4 wc_hi = *(const float4*)(W + c * A_DIM + a0 + 4);
            const float wcv[8] = {wc_lo.x, wc_lo.y, wc_lo.z, wc_lo.w,
                                  wc_hi.x, wc_hi.y, wc_hi.z, wc_hi.w};
            float ss = 0.0f;
            #pragma unroll
            for (int j = 0; j < 8; ++j)
                ss += acc[i][j] * (wcv[j] - wyv[j]);
            s[i] = ss;
        }
    }
    const int ag = t >> 3;
    *(float4*)&Psum[ag][c0]     = make_float4(s[0], s[1], s[2], s[3]);
    *(float4*)&Psum[ag][c0 + 4] = make_float4(s[4], s[5], s[6], s[7]);
    __syncthreads();

    if (t < C_CLS) {
        float r = 0.0f;
        #pragma unroll
        for (int g = 0; g < 32; ++g) r += Psum[g][t];
        Spart[(size_t)kc * C_CLS * C_CLS + y * C_CLS + t] = r;
    }

    // ---- signal: canonical threadfence-reduction pattern ----
    __threadfence();            // release prior global stores (agent scope)
    __syncthreads();
    if (t == 0)
        __hip_atomic_store(&flags[b], FLAG_READY, __ATOMIC_RELEASE,
                           __HIP_MEMORY_SCOPE_AGENT);

    if (b >= LOSS_BLOCKS) return;   // free the CU for the spinners

    // ---- wait for all 512 chunks ----
    for (int i = t; i < NBLK; i += 256) {
        while (__hip_atomic_load(&flags[i], __ATOMIC_RELAXED,
                                 __HIP_MEMORY_SCOPE_AGENT) != FLAG_READY)
            __builtin_amdgcn_s_sleep(1);
    }
    __syncthreads();
    __threadfence();            // acquire: invalidate stale L1/L2 for Spart

    // ---- phase 2: softmax cross-entropy, 8 rows per wave ----
    const float lam = 0.5f * lambda_p[0];
    float acc_nll = 0.0f;
    #pragma unroll
    for (int r = 0; r < 8; ++r) {
        const int yr = pf_y[r];
        float sp = 0.0f;
        #pragma unroll
        for (int k = 0; k < KCHUNK; ++k)
            sp += Spart[(size_t)k * C_CLS * C_CLS + yr * C_CLS + lane];
        const float logit = pf_pred[r] + lam * sp;

        float m = logit;
        #pragma unroll
        for (int off = 32; off > 0; off >>= 1)
            m = fmaxf(m, __shfl_xor(m, off, 64));
        float e = __expf(logit - m);
        float ssum = e;
        #pragma unroll
        for (int off = 32; off > 0; off >>= 1)
            ssum += __shfl_xor(ssum, off, 64);
        const float ly = __shfl(logit, yr, 64);
        acc_nll += logf(ssum) + m - ly;
    }

    if (lane == 0) wsum[t >> 6] = acc_nll;
    __syncthreads();
    if (t == 0) {
        const float blk = wsum[0] + wsum[1] + wsum[2] + wsum[3];
        atomicAdd(out, blk * (1.0f / (float)N_ROWS));
    }
}

// ---------------------------------------------------------------------------
extern "C" void kernel_launch(void* const* d_in, const int* in_sizes, int n_in,
                              void* d_out, int out_size, void* d_ws, size_t ws_size,
                              hipStream_t stream) {
    (void)in_sizes; (void)n_in; (void)out_size; (void)ws_size;
    const float* W      = (const float*)d_in[0];   // fc_weight [64][256]
    // d_in[1] = features (unused by the reference computation)
    const float* pred   = (const float*)d_in[2];   // [4096][64]
    const int*   labels = (const int*)d_in[3];     // [4096]
    const float* lam    = (const float*)d_in[4];   // scalar
    const float* CV     = (const float*)d_in[5];   // [64][256][256]
    float* out = (float*)d_out;

    float*        Spart = (float*)d_ws;                            // 128 KB
    unsigned int* flags = (unsigned int*)((char*)d_ws + KCHUNK * C_CLS * C_CLS * sizeof(float));
    // flags are NOT pre-zeroed: harness poisons ws to 0xAA... != FLAG_READY(1),
    // and the spin condition is "!= 1", so any non-1 initial state is correct.

    fused_kernel<<<dim3(NBLK), dim3(256), 0, stream>>>(
        W, CV, pred, labels, lam, Spart, flags, out);
}

// Round 5
// 89.863 us; speedup vs baseline: 1.5139x; 1.5139x over previous
//
#include <hip/hip_runtime.h>

// Problem constants (from setup_inputs): N=4096, C=64, A=256
#define N_ROWS 4096
#define C_CLS  64
#define A_DIM  256
#define BK     32           // K-chunk (over b) per block in kernel A
#define KCHUNK (A_DIM / BK) // 8
#define LOSS_BLOCKS 256     // kernel B blocks (4 waves each, 4 rows/wave)

// ---------------------------------------------------------------------------
// Kernel A: Spart[y][c][kc] = partial over b-chunk kc of (w_c-w_y)^T CV[y] (w_c-w_y)
// T[c][a] = sum_b D[c][b] * CV[y][b][a]  (CV symmetric -> row reads)
// S[c]    = sum_a D[c][a] * T[c][a]; linear in T so per-chunk partials sum.
// grid = 64*KCHUNK = 512 blocks (2 blocks/CU). Layout [y][c][kc] makes the
// loss-phase chunk-sum two float4 loads (32B contiguous per (y,c)).
// Block 0 also zeroes out[0] (kernel B accumulates into it atomically; A
// fully precedes B in stream order).
// ---------------------------------------------------------------------------
__global__ __launch_bounds__(256) void qform_kernel(
    const float* __restrict__ W,      // [C][A]
    const float* __restrict__ CV,     // [C][A][A]
    float* __restrict__ Spart,        // [C][C][KCHUNK]
    float* __restrict__ out)          // [1]
{
    __shared__ float Vt[BK][A_DIM];   // 32 KB : Vt[k][a] = CV[y][kb+k][a]
    __shared__ float Dt[BK][C_CLS];   //  8 KB : Dt[k][c] = W[c][kb+k]-W[y][kb+k]
    __shared__ float Psum[32][C_CLS]; //  8 KB : per-(a-group) partial S

    const int t  = threadIdx.x;
    const int y  = blockIdx.x >> 3;          // blockIdx / KCHUNK
    const int kc = blockIdx.x & 7;           // k-chunk index
    const int kb = kc * BK;                  // b-range start

    if (blockIdx.x == 0 && t == 0) out[0] = 0.0f;

    // ---- stage Vt: rows kb..kb+BK-1 of CV[y] (contiguous 32 KB, coalesced) ----
    {
        const float4* src = (const float4*)(CV + ((size_t)y * A_DIM * A_DIM
                                                  + (size_t)kb * A_DIM));
        float4* vdst = (float4*)&Vt[0][0];
        #pragma unroll
        for (int i = 0; i < (BK * A_DIM / 4) / 256; ++i)
            vdst[t + i * 256] = src[t + i * 256];
    }

    // ---- stage Dt (transposed diff chunk) ----
    {
        const int kq    = (t & 7) * 4;   // k = kq..kq+3
        const int chalf = t >> 3;        // 0..31
        const float4 wy = *(const float4*)(W + y * A_DIM + kb + kq);
        #pragma unroll
        for (int cc = 0; cc < 2; ++cc) {
            const int c = chalf + cc * 32;
            const float4 wc = *(const float4*)(W + c * A_DIM + kb + kq);
            Dt[kq + 0][c] = wc.x - wy.x;
            Dt[kq + 1][c] = wc.y - wy.y;
            Dt[kq + 2][c] = wc.z - wy.z;
            Dt[kq + 3][c] = wc.w - wy.w;
        }
    }
    __syncthreads();

    // ---- 8x8 register tile: c0=(t%8)*8 covers 64 c, a0=(t/8)*8 covers 256 a ----
    const int c0 = (t & 7) * 8;
    const int a0 = (t >> 3) * 8;
    float acc[8][8];
    #pragma unroll
    for (int i = 0; i < 8; ++i)
        #pragma unroll
        for (int j = 0; j < 8; ++j) acc[i][j] = 0.0f;

    #pragma unroll 2
    for (int k = 0; k < BK; ++k) {
        const float4 a_lo = *(const float4*)&Vt[k][a0];
        const float4 a_hi = *(const float4*)&Vt[k][a0 + 4];
        const float4 d_lo = *(const float4*)&Dt[k][c0];
        const float4 d_hi = *(const float4*)&Dt[k][c0 + 4];
        const float af[8] = {a_lo.x, a_lo.y, a_lo.z, a_lo.w,
                             a_hi.x, a_hi.y, a_hi.z, a_hi.w};
        const float df[8] = {d_lo.x, d_lo.y, d_lo.z, d_lo.w,
                             d_hi.x, d_hi.y, d_hi.z, d_hi.w};
        #pragma unroll
        for (int i = 0; i < 8; ++i)
            #pragma unroll
            for (int j = 0; j < 8; ++j)
                acc[i][j] += df[i] * af[j];
    }

    // ---- fused epilogue: s_i = sum_j acc[i][j] * (W[c0+i][a0+j] - W[y][a0+j]) ----
    float s[8];
    {
        const float4 wy_lo = *(const float4*)(W + y * A_DIM + a0);
        const float4 wy_hi = *(const float4*)(W + y * A_DIM + a0 + 4);
        const float wyv[8] = {wy_lo.x, wy_lo.y, wy_lo.z, wy_lo.w,
                              wy_hi.x, wy_hi.y, wy_hi.z, wy_hi.w};
        #pragma unroll
        for (int i = 0; i < 8; ++i) {
            const int c = c0 + i;
            const float4 wc_lo = *(const float4*)(W + c * A_DIM + a0);
            const float4 wc_hi = *(const float4*)(W + c * A_DIM + a0 + 4);
            const float wcv[8] = {wc_lo.x, wc_lo.y, wc_lo.z, wc_lo.w,
                                  wc_hi.x, wc_hi.y, wc_hi.z, wc_hi.w};
            float ss = 0.0f;
            #pragma unroll
            for (int j = 0; j < 8; ++j)
                ss += acc[i][j] * (wcv[j] - wyv[j]);
            s[i] = ss;
        }
    }
    // conflict-free staging: 8 consecutive floats per thread (2x ds_write_b128)
    const int ag = t >> 3;   // a-group 0..31
    *(float4*)&Psum[ag][c0]     = make_float4(s[0], s[1], s[2], s[3]);
    *(float4*)&Psum[ag][c0 + 4] = make_float4(s[4], s[5], s[6], s[7]);
    __syncthreads();

    if (t < C_CLS) {
        float r = 0.0f;
        #pragma unroll
        for (int g = 0; g < 32; ++g) r += Psum[g][t];   // stride-1 across lanes
        Spart[((size_t)y * C_CLS + t) * KCHUNK + kc] = r;
    }
}

// ---------------------------------------------------------------------------
// Kernel B: per-row softmax CE on aug = pred + 0.5*Lambda*sum_kc Spart[y][c][kc].
// 256 blocks x 4 waves, 4 rows/wave (1024 waves = 4/CU for latency hiding).
// Chunk-sum per (y,c) is 2 contiguous float4 loads (L2-hot, 128 KB region).
// One device atomicAdd per block into out[0] (zeroed by kernel A).
// ---------------------------------------------------------------------------
__global__ __launch_bounds__(256) void loss_kernel(
    const float* __restrict__ pred,    // [N][C]
    const int*   __restrict__ labels,  // [N]
    const float* __restrict__ lambda_p,
    const float* __restrict__ Spart,   // [C][C][KCHUNK]
    float* __restrict__ out)           // [1], zeroed by kernel A
{
    __shared__ float wsum[4];
    const int t    = threadIdx.x;
    const int lane = t & 63;
    const int wgid = blockIdx.x * 4 + (t >> 6);   // 0..1023
    const float lam = 0.5f * lambda_p[0];

    float acc_nll = 0.0f;
    #pragma unroll
    for (int r = 0; r < 4; ++r) {
        const int n = r * 1024 + wgid;
        const int y = labels[n];
        const float4 sp_lo = *(const float4*)&Spart[((size_t)y * C_CLS + lane) * KCHUNK];
        const float4 sp_hi = *(const float4*)&Spart[((size_t)y * C_CLS + lane) * KCHUNK + 4];
        const float sp = ((sp_lo.x + sp_lo.y) + (sp_lo.z + sp_lo.w))
                       + ((sp_hi.x + sp_hi.y) + (sp_hi.z + sp_hi.w));
        const float logit = pred[n * C_CLS + lane] + lam * sp;

        float m = logit;
        #pragma unroll
        for (int off = 32; off > 0; off >>= 1)
            m = fmaxf(m, __shfl_xor(m, off, 64));
        float e = __expf(logit - m);
        float ssum = e;
        #pragma unroll
        for (int off = 32; off > 0; off >>= 1)
            ssum += __shfl_xor(ssum, off, 64);
        const float ly = __shfl(logit, y, 64);
        acc_nll += logf(ssum) + m - ly;
    }

    if (lane == 0) wsum[t >> 6] = acc_nll;
    __syncthreads();
    if (t == 0) {
        const float blk = wsum[0] + wsum[1] + wsum[2] + wsum[3];
        atomicAdd(out, blk * (1.0f / (float)N_ROWS));
    }
}

// ---------------------------------------------------------------------------
extern "C" void kernel_launch(void* const* d_in, const int* in_sizes, int n_in,
                              void* d_out, int out_size, void* d_ws, size_t ws_size,
                              hipStream_t stream) {
    (void)in_sizes; (void)n_in; (void)out_size; (void)ws_size;
    const float* W      = (const float*)d_in[0];   // fc_weight [64][256]
    // d_in[1] = features (unused by the reference computation)
    const float* pred   = (const float*)d_in[2];   // [4096][64]
    const int*   labels = (const int*)d_in[3];     // [4096]
    const float* lam    = (const float*)d_in[4];   // scalar
    const float* CV     = (const float*)d_in[5];   // [64][256][256]
    float* out = (float*)d_out;

    float* Spart = (float*)d_ws;                   // 64*64*8 floats = 128 KB

    qform_kernel<<<dim3(C_CLS * KCHUNK), dim3(256), 0, stream>>>(W, CV, Spart, out);
    loss_kernel<<<dim3(LOSS_BLOCKS), dim3(256), 0, stream>>>(pred, labels, lam, Spart, out);
}